// Round 18
// baseline (24040.549 us; speedup 1.0000x reference)
//
#include <hip/hip_runtime.h>
#include <cmath>

// HM-LSTM forward, MI355X. Round 18 = r17 with the residency ballast FIXED.
// r17's LDS_Block_Size stayed 18944: the unused extern __shared__ was
// compiled out, so the 70KB dynamic request never allocated and 4 WGs/CU
// packing persisted (Occupancy 24.8% = 4x512/2048 on 64 CUs; 128 WGs/XCD
// need the full 9.4MB pack -> L2 thrash, FETCH 21.4GB). Fix: REFERENCE the
// dynamic LDS behind a runtime-false-but-unprovable guard so it's allocated:
// static 18.5KB + 70KB = 88.5KB > 80KB -> hard 1 WG/CU -> 256 WGs spread
// over all 256 CUs -> 32 WGs/XCD -> physical-XCD shard binding balances ->
// each XCD reads only its ~1.05MB slice (L2-resident).
// Kernel logic byte-identical to r16/r17 (passed + replayed clean).

#define Hh    256
#define Bb    64
#define Tt    512
#define GC    1025
#define NGRP  32
#define RPG   2          // rows per group
#define WDOG  400000
#define WBOOT 2000000

__device__ __forceinline__ void g_st(float* p, float v) {
    __hip_atomic_store(p, v, __ATOMIC_RELAXED, __HIP_MEMORY_SCOPE_AGENT);
}
__device__ __forceinline__ unsigned int a_add(unsigned int* p, unsigned int v) {
    return __hip_atomic_fetch_add(p, v, __ATOMIC_RELAXED, __HIP_MEMORY_SCOPE_AGENT);
}
__device__ __forceinline__ unsigned int a_ld32(const unsigned int* p) {
    return __hip_atomic_load(p, __ATOMIC_RELAXED, __HIP_MEMORY_SCOPE_AGENT);
}
__device__ __forceinline__ unsigned int xcc_id() {
    unsigned int x;
    asm("s_getreg_b32 %0, hwreg(HW_REG_XCC_ID)" : "=s"(x));
    return x & 7u;
}

// ---------------------------------------------------------------------------
// Prep: pack weights k4-blocked: w4[((l*192 + k/4)*1024 + col)*4 + k%4]
// (cols 0..1023 = gates f,i,o,g), z column -> wz[l*768+k].
// ---------------------------------------------------------------------------
struct WSrc { const float* wb[3]; const float* wr[3]; const float* wt[3]; };

__global__ __launch_bounds__(256) void build_w4(WSrc S, float* __restrict__ w4,
                                                float* __restrict__ wz) {
    const int gk = blockIdx.x;           // 0..2047
    int l, k;
    if (gk < 768)       { l = 0; k = gk; }
    else if (gk < 1536) { l = 1; k = gk - 768; }
    else                { l = 2; k = gk - 1536; }   // 512 rows
    const float* src;
    if (k < 256)      src = S.wb[l] + (size_t)k * GC;
    else if (k < 512) src = S.wr[l] + (size_t)(k - 256) * GC;
    else              src = S.wt[l] + (size_t)(k - 512) * GC;
    float* dst = w4 + (((size_t)l * 192 + (k >> 2)) * 1024) * 4 + (k & 3);
#pragma unroll
    for (int i = 0; i < 5; ++i) {
        int c = i * 256 + threadIdx.x;
        if (c < 1024)       dst[(size_t)c * 4] = src[c];
        else if (c == 1024) wz[l * 768 + k] = src[c];
    }
}

// ---------------------------------------------------------------------------
// Main chain kernel. Grid 256 x 512, 70KB dynamic LDS ballast (1 WG/CU).
// Role (group, shard) from physical XCD; each group owns 2 batch rows.
// ---------------------------------------------------------------------------
struct PK {
    const float* x;         // (64,512,256)
    const float* w4;        // k4-packed weights
    const float* wz;        // [3][768] z columns
    const float* bias[3];   // (1025,)
    float* zws;             // z state: ((row*1539)+(t*3+l))*32
    unsigned int* bar;      // [g*32] group lines (32 groups)
    unsigned int* asn;      // [x*32] per-XCD cnt; [512] boot cnt
    float* out_h;           // (64,512,768) — doubles as h state
    float* out_z;           // (64,512,3)
};

extern __shared__ float dyn_pad[];   // residency ballast

__global__ __launch_bounds__(512, 1) void chain_kernel(PK P) {
    __shared__ float A[768 * RPG];           // [k][row] gated inputs, 6KB
    __shared__ float red[8][128][3];         // [wave][col_local][row+pad], 12KB
    __shared__ float zbS[RPG], zoS[RPG];
    __shared__ unsigned int sRole;           // group*8 + shard

    const int tid   = threadIdx.x;
    const int lane  = tid & 63;
    const int wave  = tid >> 6;              // 0..7

    // Force dynamic-LDS allocation: never true at runtime, not provable.
    if (P.out_h == nullptr) dyn_pad[tid] = 0.0f;

    // ---- prologue: physical-XCD role assignment (one-time) ----
    if (tid == 0) {
        const unsigned int x = xcc_id();
        const unsigned int idx = a_add(&P.asn[x * 32], 1u);
        a_add(&P.asn[512], 1u);
        int it = 0;
        while (a_ld32(&P.asn[512]) < 256u && it < WBOOT) { __builtin_amdgcn_s_sleep(8); ++it; }
        bool bal = (it < WBOOT) && (idx < 32u);
        if (bal) {
#pragma unroll
            for (int q = 0; q < 8; ++q)
                if (a_ld32(&P.asn[q * 32]) != 32u) bal = false;
        }
        sRole = bal ? (idx * 8u + x)
                    : ((unsigned)(blockIdx.x >> 3) * 8u + (blockIdx.x & 7));
    }
    __syncthreads();
    const int group = sRole >> 3;
    const int shard = sRole & 7;
    const int row0  = group * RPG;

    unsigned int* grpCnt = P.bar + group * 32;
    unsigned int stage = 0;
    bool broken = false;

    float creg[3] = {0.f, 0.f, 0.f};         // (tid<64): own (row,j) cell state
    float hreg[3] = {0.f, 0.f, 0.f};

    // GEMV lane columns (within [0,1024)): gate blocks {gi0, gi0+2}
    const int gi0 = lane >> 5;               // 0 or 1
    const int jl  = lane & 31;
    const size_t cA = (size_t)(gi0 * 256 + shard * 32 + jl);
    const size_t cB = (size_t)((gi0 + 2) * 256 + shard * 32 + jl);

    for (int t = 0; t < Tt; ++t) {
#pragma unroll
        for (int l = 0; l < 3; ++l) {
            const int K = (l < 2) ? 768 : 512;
            const float* __restrict__ bias = P.bias[l];

            // ---- 1. per-row gate scalars ----
            if (tid < RPG) {
                const int r = row0 + tid;
                float zo = (t > 0) ? P.zws[((size_t)r * 1539 + ((t - 1) * 3 + l)) * 32] : 0.f;
                float zb = (l == 0) ? 1.f
                         : P.zws[((size_t)r * 1539 + (t * 3 + l - 1)) * 32];
                zoS[tid] = zo; zbS[tid] = zb;
            }
            __syncthreads();

            // ---- 2. stage gated inputs A[k][row] ----
            for (int e = tid; e < RPG * K; e += 512) {
                const int row = (e < K) ? 0 : 1;
                const int k   = e - row * K;
                const int r   = row0 + row;
                float v;
                if (k < 256) {
                    float b = (l == 0)
                        ? P.x[((size_t)r * Tt + t) * 256 + k]
                        : P.out_h[((size_t)r * Tt + t) * 768 + (l - 1) * 256 + k];
                    v = zbS[row] * b;
                } else if (k < 512) {
                    v = (t > 0)
                        ? P.out_h[((size_t)r * Tt + (t - 1)) * 768 + l * 256 + (k - 256)]
                        : 0.f;
                } else {
                    float tp = (t > 0)
                        ? P.out_h[((size_t)r * Tt + (t - 1)) * 768 + (l + 1) * 256 + (k - 512)]
                        : 0.f;
                    v = zoS[row] * tp;
                }
                A[k * RPG + row] = v;
            }
            __syncthreads();

            // ---- 3. GEMV: wave = k4-block chunk; lane = 2 cols x 2 rows ----
            {
                const int Kb  = K >> 5;              // k4-blocks per wave (24/16)
                const int kb0 = wave * Kb;
                const float4* __restrict__ W4l =
                    (const float4*)P.w4 + (size_t)l * 192 * 1024;
                float acc0[RPG], acc1[RPG];
#pragma unroll
                for (int r = 0; r < RPG; ++r) { acc0[r] = 0.f; acc1[r] = 0.f; }
                for (int kb = kb0; kb < kb0 + Kb; ++kb) {
                    float4 w0 = W4l[(size_t)kb * 1024 + cA];
                    float4 w1 = W4l[(size_t)kb * 1024 + cB];
#pragma unroll
                    for (int q = 0; q < 4; ++q) {
                        float2 a = *(const float2*)&A[(kb * 4 + q) * RPG];
                        const float wq0 = (&w0.x)[q];
                        const float wq1 = (&w1.x)[q];
                        acc0[0] += wq0 * a.x; acc0[1] += wq0 * a.y;
                        acc1[0] += wq1 * a.x; acc1[1] += wq1 * a.y;
                    }
                }
                const int cl0 = gi0 * 32 + jl;         // col_local of cA
                const int cl1 = (gi0 + 2) * 32 + jl;   // col_local of cB
#pragma unroll
                for (int r = 0; r < RPG; ++r) red[wave][cl0][r] = acc0[r];
#pragma unroll
                for (int r = 0; r < RPG; ++r) red[wave][cl1][r] = acc1[r];
            }

            // ---- 4. z column (shard 7): fp64, wave=row, lane=k strided ----
            if (shard == 7 && wave < RPG) {
                const float* __restrict__ wzl = P.wz + l * 768;
                double zp = 0.0;
                for (int k = lane; k < K; k += 64)
                    zp += (double)wzl[k] * (double)A[k * RPG + wave];
#pragma unroll
                for (int off = 32; off > 0; off >>= 1)
                    zp += __shfl_down(zp, off);
                if (lane == 0) {
                    double s = (double)bias[1024] + zp;
                    // round(clip((s+1)/2,0,1)) round-half-even == (s > 0)
                    float znew = (s > 0.0) ? 1.0f : 0.0f;
                    const int r = row0 + wave;
                    g_st(&P.zws[((size_t)r * 1539 + (t * 3 + l)) * 32], znew);
                    P.out_z[((size_t)r * Tt + t) * 3 + l] = znew;
                }
            }
            __syncthreads();

            // ---- 5. epilogue: threads 0..63 own (row, j) ----
            if (tid < RPG * 32) {
                const int row = tid >> 5;
                const int j   = tid & 31;
                const int r   = row0 + row;
                float s0 = bias[0 * Hh + shard * 32 + j];
                float s1 = bias[1 * Hh + shard * 32 + j];
                float s2 = bias[2 * Hh + shard * 32 + j];
                float s3 = bias[3 * Hh + shard * 32 + j];
#pragma unroll
                for (int w = 0; w < 8; ++w) {
                    s0 += red[w][0 * 32 + j][row];
                    s1 += red[w][1 * 32 + j][row];
                    s2 += red[w][2 * 32 + j][row];
                    s3 += red[w][3 * 32 + j][row];
                }
                float f = 1.0f / (1.0f + expf(-s0));
                float i = 1.0f / (1.0f + expf(-s1));
                float o = 1.0f / (1.0f + expf(-s2));
                float g = tanhf(s3);
                float zb_ = zbS[row];
                float zo_ = zoS[row];
                float c    = creg[l];
                float hold = hreg[l];
                float ig   = i * g;
                float cupd = f * c + ig;
                // z,zb in {0,1} exactly -> selects == reference arithmetic
                float cnew = (zo_ != 0.0f) ? ig : ((zb_ != 0.0f) ? cupd : c);
                float hnew = (zo_ == 0.0f && zb_ == 0.0f) ? hold : (o * tanhf(cnew));
                creg[l] = cnew;
                hreg[l] = hnew;
                g_st(&P.out_h[((size_t)r * Tt + t) * 768 + l * 256 + shard * 32 + j], hnew);
            }

            // ---- 6. 8-agent group barrier (r13..r17-proven RMW + poll) ----
            __syncthreads();   // drains vmcnt: h/z sc1 stores L3-visible
            if (tid == 0) {
                a_add(grpCnt, 1u);
                if (!broken) {
                    const unsigned int tgt = 8u * (stage + 1u);
                    unsigned int v = 0; int it = 0;
                    for (; it < WDOG; ++it) {
                        v = a_ld32(grpCnt);
                        if (v >= tgt) break;
                        __builtin_amdgcn_s_sleep(2);
                    }
                    broken = (v < tgt);
                }
            }
            __syncthreads();
            ++stage;
        }
    }
}

extern "C" void kernel_launch(void* const* d_in, const int* in_sizes, int n_in,
                              void* d_out, int out_size, void* d_ws, size_t ws_size,
                              hipStream_t stream) {
    (void)in_sizes; (void)n_in; (void)out_size;

    // dict order: x, Wb0,Wr0,Wt0,b0, Wb1,Wr1,Wt1,b1, Wb2,Wr2,Wt2,b2
    const float* x = (const float*)d_in[0];
    float* wsf = (float*)d_ws;

    // ws layout (floats)
    const size_t OFF_W4  = 0;                               // 3*192*1024*4
    const size_t OFF_WZ  = OFF_W4 + (size_t)3 * 192 * 1024 * 4;
    const size_t OFF_ZWS = OFF_WZ + 3 * 768 + 64;
    const size_t OFF_BAR = OFF_ZWS + (size_t)64 * 1539 * 32;
    const size_t OFF_ASN = OFF_BAR + 1024;
    const size_t OFF_END = OFF_ASN + 1024;

    float* w4  = wsf + OFF_W4;
    float* wz  = wsf + OFF_WZ;
    float* zws = wsf + OFF_ZWS;
    unsigned int* bar = (unsigned int*)(wsf + OFF_BAR);
    unsigned int* asn = (unsigned int*)(wsf + OFF_ASN);

    if (ws_size < OFF_END * sizeof(float)) return;     // ~22MB; ws proven >=110MB

    hipMemsetAsync(bar, 0, 2048 * sizeof(float), stream);   // bar + asn

    WSrc S;
    S.wb[0] = (const float*)d_in[1];  S.wr[0] = (const float*)d_in[2];  S.wt[0] = (const float*)d_in[3];
    S.wb[1] = (const float*)d_in[5];  S.wr[1] = (const float*)d_in[6];  S.wt[1] = (const float*)d_in[7];
    S.wb[2] = (const float*)d_in[9];  S.wr[2] = (const float*)d_in[10]; S.wt[2] = (const float*)d_in[11];
    build_w4<<<2048, 256, 0, stream>>>(S, w4, wz);

    PK pk;
    pk.x = x;
    pk.w4 = w4;
    pk.wz = wz;
    pk.bias[0] = (const float*)d_in[4];
    pk.bias[1] = (const float*)d_in[8];
    pk.bias[2] = (const float*)d_in[12];
    pk.zws = zws;
    pk.bar = bar;
    pk.asn = asn;
    pk.out_h = (float*)d_out;
    pk.out_z = (float*)d_out + (size_t)Bb * Tt * 768;

    // 70KB dynamic LDS (now actually referenced/allocated):
    // static ~18.5KB + 70KB = 88.5KB > 80KB -> hard 1 WG/CU cap.
    chain_kernel<<<256, 512, 70 * 1024, stream>>>(pk);
}

// Round 19
// 22922.012 us; speedup vs baseline: 1.0488x; 1.0488x over previous
//
#include <hip/hip_runtime.h>
#include <cmath>

// HM-LSTM forward, MI355X. Round 19 = r18 with a STATIC LDS ballast.
// r17/r18: dynamic-LDS ballast silently never allocated (LDS_Block_Size
// stayed 18944) -> 4 WGs/CU packing persisted -> 32-per-XCD balance check
// failed -> fallback mapping -> every XCD streams the full 9.4MB weight pack
// per stage (FETCH 21.4GB = 13.9MB/stage at ~910GB/s = the whole stage time).
// Fix: __shared__ float ballast[17920] (70KB) STATIC in the kernel with an
// unprovable fake use -> static LDS 88.5KB baked into the code object ->
// hard 1 WG/CU (verifiable via LDS_Block_Size) -> grid 256 = 32 WGs/XCD ->
// physical-XCD binding balances -> shard == own XCD -> each XCD L2 holds
// only its 1.18MB slice. Kernel logic byte-identical to r16..r18.

#define Hh    256
#define Bb    64
#define Tt    512
#define GC    1025
#define NGRP  32
#define RPG   2          // rows per group
#define WDOG  400000
#define WBOOT 2000000

__device__ __forceinline__ void g_st(float* p, float v) {
    __hip_atomic_store(p, v, __ATOMIC_RELAXED, __HIP_MEMORY_SCOPE_AGENT);
}
__device__ __forceinline__ unsigned int a_add(unsigned int* p, unsigned int v) {
    return __hip_atomic_fetch_add(p, v, __ATOMIC_RELAXED, __HIP_MEMORY_SCOPE_AGENT);
}
__device__ __forceinline__ unsigned int a_ld32(const unsigned int* p) {
    return __hip_atomic_load(p, __ATOMIC_RELAXED, __HIP_MEMORY_SCOPE_AGENT);
}
__device__ __forceinline__ unsigned int xcc_id() {
    unsigned int x;
    asm("s_getreg_b32 %0, hwreg(HW_REG_XCC_ID)" : "=s"(x));
    return x & 7u;
}

// ---------------------------------------------------------------------------
// Prep: pack weights k4-blocked: w4[((l*192 + k/4)*1024 + col)*4 + k%4]
// (cols 0..1023 = gates f,i,o,g), z column -> wz[l*768+k].
// ---------------------------------------------------------------------------
struct WSrc { const float* wb[3]; const float* wr[3]; const float* wt[3]; };

__global__ __launch_bounds__(256) void build_w4(WSrc S, float* __restrict__ w4,
                                                float* __restrict__ wz) {
    const int gk = blockIdx.x;           // 0..2047
    int l, k;
    if (gk < 768)       { l = 0; k = gk; }
    else if (gk < 1536) { l = 1; k = gk - 768; }
    else                { l = 2; k = gk - 1536; }   // 512 rows
    const float* src;
    if (k < 256)      src = S.wb[l] + (size_t)k * GC;
    else if (k < 512) src = S.wr[l] + (size_t)(k - 256) * GC;
    else              src = S.wt[l] + (size_t)(k - 512) * GC;
    float* dst = w4 + (((size_t)l * 192 + (k >> 2)) * 1024) * 4 + (k & 3);
#pragma unroll
    for (int i = 0; i < 5; ++i) {
        int c = i * 256 + threadIdx.x;
        if (c < 1024)       dst[(size_t)c * 4] = src[c];
        else if (c == 1024) wz[l * 768 + k] = src[c];
    }
}

// ---------------------------------------------------------------------------
// Main chain kernel. Grid 256 x 512, 70KB STATIC ballast (1 WG/CU).
// Role (group, shard) from physical XCD; each group owns 2 batch rows.
// ---------------------------------------------------------------------------
struct PK {
    const float* x;         // (64,512,256)
    const float* w4;        // k4-packed weights
    const float* wz;        // [3][768] z columns
    const float* bias[3];   // (1025,)
    float* zws;             // z state: ((row*1539)+(t*3+l))*32
    unsigned int* bar;      // [g*32] group lines (32 groups)
    unsigned int* asn;      // [x*32] per-XCD cnt; [512] boot cnt
    float* out_h;           // (64,512,768) — doubles as h state
    float* out_z;           // (64,512,3)
};

__global__ __launch_bounds__(512, 1) void chain_kernel(PK P) {
    __shared__ float A[768 * RPG];           // [k][row] gated inputs, 6KB
    __shared__ float red[8][128][3];         // [wave][col_local][row+pad], 12KB
    __shared__ float zbS[RPG], zoS[RPG];
    __shared__ unsigned int sRole;           // group*8 + shard
    __shared__ float ballast[17920];         // 70KB residency ballast (static)

    const int tid   = threadIdx.x;
    const int lane  = tid & 63;
    const int wave  = tid >> 6;              // 0..7

    // Unprovable fake use so the static ballast is never elided.
    if (P.out_h == nullptr) {
        ballast[tid] = (float)tid;
        g_st(&P.out_z[tid], ballast[tid ^ 1]);
    }

    // ---- prologue: physical-XCD role assignment (one-time) ----
    if (tid == 0) {
        const unsigned int x = xcc_id();
        const unsigned int idx = a_add(&P.asn[x * 32], 1u);
        a_add(&P.asn[512], 1u);
        int it = 0;
        while (a_ld32(&P.asn[512]) < 256u && it < WBOOT) { __builtin_amdgcn_s_sleep(8); ++it; }
        bool bal = (it < WBOOT) && (idx < 32u);
        if (bal) {
#pragma unroll
            for (int q = 0; q < 8; ++q)
                if (a_ld32(&P.asn[q * 32]) != 32u) bal = false;
        }
        sRole = bal ? (idx * 8u + x)
                    : ((unsigned)(blockIdx.x >> 3) * 8u + (blockIdx.x & 7));
    }
    __syncthreads();
    const int group = sRole >> 3;
    const int shard = sRole & 7;
    const int row0  = group * RPG;

    unsigned int* grpCnt = P.bar + group * 32;
    unsigned int stage = 0;
    bool broken = false;

    float creg[3] = {0.f, 0.f, 0.f};         // (tid<64): own (row,j) cell state
    float hreg[3] = {0.f, 0.f, 0.f};

    // GEMV lane columns (within [0,1024)): gate blocks {gi0, gi0+2}
    const int gi0 = lane >> 5;               // 0 or 1
    const int jl  = lane & 31;
    const size_t cA = (size_t)(gi0 * 256 + shard * 32 + jl);
    const size_t cB = (size_t)((gi0 + 2) * 256 + shard * 32 + jl);

    for (int t = 0; t < Tt; ++t) {
#pragma unroll
        for (int l = 0; l < 3; ++l) {
            const int K = (l < 2) ? 768 : 512;
            const float* __restrict__ bias = P.bias[l];

            // ---- 1. per-row gate scalars ----
            if (tid < RPG) {
                const int r = row0 + tid;
                float zo = (t > 0) ? P.zws[((size_t)r * 1539 + ((t - 1) * 3 + l)) * 32] : 0.f;
                float zb = (l == 0) ? 1.f
                         : P.zws[((size_t)r * 1539 + (t * 3 + l - 1)) * 32];
                zoS[tid] = zo; zbS[tid] = zb;
            }
            __syncthreads();

            // ---- 2. stage gated inputs A[k][row] ----
            for (int e = tid; e < RPG * K; e += 512) {
                const int row = (e < K) ? 0 : 1;
                const int k   = e - row * K;
                const int r   = row0 + row;
                float v;
                if (k < 256) {
                    float b = (l == 0)
                        ? P.x[((size_t)r * Tt + t) * 256 + k]
                        : P.out_h[((size_t)r * Tt + t) * 768 + (l - 1) * 256 + k];
                    v = zbS[row] * b;
                } else if (k < 512) {
                    v = (t > 0)
                        ? P.out_h[((size_t)r * Tt + (t - 1)) * 768 + l * 256 + (k - 256)]
                        : 0.f;
                } else {
                    float tp = (t > 0)
                        ? P.out_h[((size_t)r * Tt + (t - 1)) * 768 + (l + 1) * 256 + (k - 512)]
                        : 0.f;
                    v = zoS[row] * tp;
                }
                A[k * RPG + row] = v;
            }
            __syncthreads();

            // ---- 3. GEMV: wave = k4-block chunk; lane = 2 cols x 2 rows ----
            {
                const int Kb  = K >> 5;              // k4-blocks per wave (24/16)
                const int kb0 = wave * Kb;
                const float4* __restrict__ W4l =
                    (const float4*)P.w4 + (size_t)l * 192 * 1024;
                float acc0[RPG], acc1[RPG];
#pragma unroll
                for (int r = 0; r < RPG; ++r) { acc0[r] = 0.f; acc1[r] = 0.f; }
                for (int kb = kb0; kb < kb0 + Kb; ++kb) {
                    float4 w0 = W4l[(size_t)kb * 1024 + cA];
                    float4 w1 = W4l[(size_t)kb * 1024 + cB];
#pragma unroll
                    for (int q = 0; q < 4; ++q) {
                        float2 a = *(const float2*)&A[(kb * 4 + q) * RPG];
                        const float wq0 = (&w0.x)[q];
                        const float wq1 = (&w1.x)[q];
                        acc0[0] += wq0 * a.x; acc0[1] += wq0 * a.y;
                        acc1[0] += wq1 * a.x; acc1[1] += wq1 * a.y;
                    }
                }
                const int cl0 = gi0 * 32 + jl;         // col_local of cA
                const int cl1 = (gi0 + 2) * 32 + jl;   // col_local of cB
#pragma unroll
                for (int r = 0; r < RPG; ++r) red[wave][cl0][r] = acc0[r];
#pragma unroll
                for (int r = 0; r < RPG; ++r) red[wave][cl1][r] = acc1[r];
            }

            // ---- 4. z column (shard 7): fp64, wave=row, lane=k strided ----
            if (shard == 7 && wave < RPG) {
                const float* __restrict__ wzl = P.wz + l * 768;
                double zp = 0.0;
                for (int k = lane; k < K; k += 64)
                    zp += (double)wzl[k] * (double)A[k * RPG + wave];
#pragma unroll
                for (int off = 32; off > 0; off >>= 1)
                    zp += __shfl_down(zp, off);
                if (lane == 0) {
                    double s = (double)bias[1024] + zp;
                    // round(clip((s+1)/2,0,1)) round-half-even == (s > 0)
                    float znew = (s > 0.0) ? 1.0f : 0.0f;
                    const int r = row0 + wave;
                    g_st(&P.zws[((size_t)r * 1539 + (t * 3 + l)) * 32], znew);
                    P.out_z[((size_t)r * Tt + t) * 3 + l] = znew;
                }
            }
            __syncthreads();

            // ---- 5. epilogue: threads 0..63 own (row, j) ----
            if (tid < RPG * 32) {
                const int row = tid >> 5;
                const int j   = tid & 31;
                const int r   = row0 + row;
                float s0 = bias[0 * Hh + shard * 32 + j];
                float s1 = bias[1 * Hh + shard * 32 + j];
                float s2 = bias[2 * Hh + shard * 32 + j];
                float s3 = bias[3 * Hh + shard * 32 + j];
#pragma unroll
                for (int w = 0; w < 8; ++w) {
                    s0 += red[w][0 * 32 + j][row];
                    s1 += red[w][1 * 32 + j][row];
                    s2 += red[w][2 * 32 + j][row];
                    s3 += red[w][3 * 32 + j][row];
                }
                float f = 1.0f / (1.0f + expf(-s0));
                float i = 1.0f / (1.0f + expf(-s1));
                float o = 1.0f / (1.0f + expf(-s2));
                float g = tanhf(s3);
                float zb_ = zbS[row];
                float zo_ = zoS[row];
                float c    = creg[l];
                float hold = hreg[l];
                float ig   = i * g;
                float cupd = f * c + ig;
                // z,zb in {0,1} exactly -> selects == reference arithmetic
                float cnew = (zo_ != 0.0f) ? ig : ((zb_ != 0.0f) ? cupd : c);
                float hnew = (zo_ == 0.0f && zb_ == 0.0f) ? hold : (o * tanhf(cnew));
                creg[l] = cnew;
                hreg[l] = hnew;
                g_st(&P.out_h[((size_t)r * Tt + t) * 768 + l * 256 + shard * 32 + j], hnew);
            }

            // ---- 6. 8-agent group barrier (r13..r18-proven RMW + poll) ----
            __syncthreads();   // drains vmcnt: h/z sc1 stores L3-visible
            if (tid == 0) {
                a_add(grpCnt, 1u);
                if (!broken) {
                    const unsigned int tgt = 8u * (stage + 1u);
                    unsigned int v = 0; int it = 0;
                    for (; it < WDOG; ++it) {
                        v = a_ld32(grpCnt);
                        if (v >= tgt) break;
                        __builtin_amdgcn_s_sleep(2);
                    }
                    broken = (v < tgt);
                }
            }
            __syncthreads();
            ++stage;
        }
    }
}

extern "C" void kernel_launch(void* const* d_in, const int* in_sizes, int n_in,
                              void* d_out, int out_size, void* d_ws, size_t ws_size,
                              hipStream_t stream) {
    (void)in_sizes; (void)n_in; (void)out_size;

    // dict order: x, Wb0,Wr0,Wt0,b0, Wb1,Wr1,Wt1,b1, Wb2,Wr2,Wt2,b2
    const float* x = (const float*)d_in[0];
    float* wsf = (float*)d_ws;

    // ws layout (floats)
    const size_t OFF_W4  = 0;                               // 3*192*1024*4
    const size_t OFF_WZ  = OFF_W4 + (size_t)3 * 192 * 1024 * 4;
    const size_t OFF_ZWS = OFF_WZ + 3 * 768 + 64;
    const size_t OFF_BAR = OFF_ZWS + (size_t)64 * 1539 * 32;
    const size_t OFF_ASN = OFF_BAR + 1024;
    const size_t OFF_END = OFF_ASN + 1024;

    float* w4  = wsf + OFF_W4;
    float* wz  = wsf + OFF_WZ;
    float* zws = wsf + OFF_ZWS;
    unsigned int* bar = (unsigned int*)(wsf + OFF_BAR);
    unsigned int* asn = (unsigned int*)(wsf + OFF_ASN);

    if (ws_size < OFF_END * sizeof(float)) return;     // ~22MB; ws proven >=110MB

    hipMemsetAsync(bar, 0, 2048 * sizeof(float), stream);   // bar + asn

    WSrc S;
    S.wb[0] = (const float*)d_in[1];  S.wr[0] = (const float*)d_in[2];  S.wt[0] = (const float*)d_in[3];
    S.wb[1] = (const float*)d_in[5];  S.wr[1] = (const float*)d_in[6];  S.wt[1] = (const float*)d_in[7];
    S.wb[2] = (const float*)d_in[9];  S.wr[2] = (const float*)d_in[10]; S.wt[2] = (const float*)d_in[11];
    build_w4<<<2048, 256, 0, stream>>>(S, w4, wz);

    PK pk;
    pk.x = x;
    pk.w4 = w4;
    pk.wz = wz;
    pk.bias[0] = (const float*)d_in[4];
    pk.bias[1] = (const float*)d_in[8];
    pk.bias[2] = (const float*)d_in[12];
    pk.zws = zws;
    pk.bar = bar;
    pk.asn = asn;
    pk.out_h = (float*)d_out;
    pk.out_z = (float*)d_out + (size_t)Bb * Tt * 768;

    chain_kernel<<<256, 512, 0, stream>>>(pk);
}

// Round 21
// 10870.464 us; speedup vs baseline: 2.2115x; 2.1087x over previous
//
#include <hip/hip_runtime.h>
#include <cmath>

// HM-LSTM forward, MI355X. Round 21 = r20 + STALE-L2-PROOF consumer reads.
// r20 (10.9ms pre-timing PASS; contiguous per-shard pack fixed the L2 set
// thrash) diverged on replay (0.64): consumers read out_h/zws with NORMAL
// cached loads while producers write sc1 -> a consumer XCD's L2 (via HW
// prefetch of adjacent lines in the same 768-float (r,t) row) can cache a
// line BEFORE the producer's sc1 write reaches L3 -> stale read (0xAA on
// first timed replay). Fix: ALL cross-WG-produced state reads (out_h staging,
// zws gate scalars) use sc1 agent-scope loads (always L3-coherent). x,
// weights, bias stay cached. Everything else byte-identical to r20:
// per-shard dense pack, 70KB static ballast (1 WG/CU verified), physical-XCD
// binding + fallback, 8-agent group barrier, fp64 z (s>0), sc1 h-stores.

#define Hh    256
#define Bb    64
#define Tt    512
#define GC    1025
#define NGRP  32
#define RPG   2          // rows per group
#define WDOG  400000
#define WBOOT 2000000

__device__ __forceinline__ void g_st(float* p, float v) {
    __hip_atomic_store(p, v, __ATOMIC_RELAXED, __HIP_MEMORY_SCOPE_AGENT);
}
__device__ __forceinline__ float g_ldf(const float* p) {
    return __hip_atomic_load(p, __ATOMIC_RELAXED, __HIP_MEMORY_SCOPE_AGENT);
}
__device__ __forceinline__ unsigned int a_add(unsigned int* p, unsigned int v) {
    return __hip_atomic_fetch_add(p, v, __ATOMIC_RELAXED, __HIP_MEMORY_SCOPE_AGENT);
}
__device__ __forceinline__ unsigned int a_ld32(const unsigned int* p) {
    return __hip_atomic_load(p, __ATOMIC_RELAXED, __HIP_MEMORY_SCOPE_AGENT);
}
__device__ __forceinline__ unsigned int xcc_id() {
    unsigned int x;
    asm("s_getreg_b32 %0, hwreg(HW_REG_XCC_ID)" : "=s"(x));
    return x & 7u;
}

// ---------------------------------------------------------------------------
// Prep: per-shard dense pack:
//   w4s[(((s*3 + l)*192 + k/4)*128 + cl)*4 + k%4],  cl = gate*32 + jl,
//   source col = gate*256 + s*32 + jl.  z column -> wz[l*768+k].
// ---------------------------------------------------------------------------
struct WSrc { const float* wb[3]; const float* wr[3]; const float* wt[3]; };

__global__ __launch_bounds__(256) void build_w4s(WSrc S, float* __restrict__ w4s,
                                                 float* __restrict__ wz) {
    const int gk = blockIdx.x;           // 0..2047 = (l,k)
    int l, k;
    if (gk < 768)       { l = 0; k = gk; }
    else if (gk < 1536) { l = 1; k = gk - 768; }
    else                { l = 2; k = gk - 1536; }   // 512 rows
    const float* src;
    if (k < 256)      src = S.wb[l] + (size_t)k * GC;
    else if (k < 512) src = S.wr[l] + (size_t)(k - 256) * GC;
    else              src = S.wt[l] + (size_t)(k - 512) * GC;
#pragma unroll
    for (int it = 0; it < 4; ++it) {
        const int idx = it * 256 + threadIdx.x;     // 0..1023 = (s, cl)
        const int s  = idx >> 7;
        const int cl = idx & 127;
        const int scol = (cl >> 5) * 256 + s * 32 + (cl & 31);
        w4s[((((size_t)s * 3 + l) * 192 + (k >> 2)) * 128 + cl) * 4 + (k & 3)] = src[scol];
    }
    if (threadIdx.x == 0) wz[l * 768 + k] = src[1024];
}

// ---------------------------------------------------------------------------
// Main chain kernel. Grid 256 x 512, 70KB static ballast (1 WG/CU verified).
// Role (group, shard) from physical XCD; each group owns 2 batch rows.
// ---------------------------------------------------------------------------
struct PK {
    const float* x;         // (64,512,256)
    const float* w4s;       // per-shard dense packed weights
    const float* wz;        // [3][768] z columns
    const float* bias[3];   // (1025,)
    float* zws;             // z state: ((row*1539)+(t*3+l))*32
    unsigned int* bar;      // [g*32] group lines (32 groups)
    unsigned int* asn;      // [x*32] per-XCD cnt; [512] boot cnt
    float* out_h;           // (64,512,768) — doubles as h state
    float* out_z;           // (64,512,3)
};

__global__ __launch_bounds__(512, 1) void chain_kernel(PK P) {
    __shared__ float A[768 * RPG];           // [k][row] gated inputs, 6KB
    __shared__ float red[8][128][3];         // [wave][col_local][row+pad], 12KB
    __shared__ float zbS[RPG], zoS[RPG];
    __shared__ unsigned int sRole;           // group*8 + shard
    __shared__ float ballast[17920];         // 70KB residency ballast (static)

    const int tid   = threadIdx.x;
    const int lane  = tid & 63;
    const int wave  = tid >> 6;              // 0..7

    // Unprovable fake use so the static ballast is never elided.
    if (P.out_h == nullptr) {
        ballast[tid] = (float)tid;
        g_st(&P.out_z[tid], ballast[tid ^ 1]);
    }

    // ---- prologue: physical-XCD role assignment (one-time) ----
    if (tid == 0) {
        const unsigned int x = xcc_id();
        const unsigned int idx = a_add(&P.asn[x * 32], 1u);
        a_add(&P.asn[512], 1u);
        int it = 0;
        while (a_ld32(&P.asn[512]) < 256u && it < WBOOT) { __builtin_amdgcn_s_sleep(8); ++it; }
        bool bal = (it < WBOOT) && (idx < 32u);
        if (bal) {
#pragma unroll
            for (int q = 0; q < 8; ++q)
                if (a_ld32(&P.asn[q * 32]) != 32u) bal = false;
        }
        sRole = bal ? (idx * 8u + x)
                    : ((unsigned)(blockIdx.x >> 3) * 8u + (blockIdx.x & 7));
    }
    __syncthreads();
    const int group = sRole >> 3;
    const int shard = sRole & 7;
    const int row0  = group * RPG;

    unsigned int* grpCnt = P.bar + group * 32;
    unsigned int stage = 0;
    bool broken = false;

    float creg[3] = {0.f, 0.f, 0.f};         // (tid<64): own (row,j) cell state
    float hreg[3] = {0.f, 0.f, 0.f};

    // GEMV lane columns: cl0 in gate gi0, cl1 in gate gi0+2
    const int gi0 = lane >> 5;               // 0 or 1
    const int jl  = lane & 31;
    const int cl0 = gi0 * 32 + jl;
    const int cl1 = (gi0 + 2) * 32 + jl;

    for (int t = 0; t < Tt; ++t) {
#pragma unroll
        for (int l = 0; l < 3; ++l) {
            const int K = (l < 2) ? 768 : 512;
            const float* __restrict__ bias = P.bias[l];

            // ---- 1. per-row gate scalars (sc1 reads: L3-coherent) ----
            if (tid < RPG) {
                const int r = row0 + tid;
                float zo = (t > 0) ? g_ldf(&P.zws[((size_t)r * 1539 + ((t - 1) * 3 + l)) * 32]) : 0.f;
                float zb = (l == 0) ? 1.f
                         : g_ldf(&P.zws[((size_t)r * 1539 + (t * 3 + l - 1)) * 32]);
                zoS[tid] = zo; zbS[tid] = zb;
            }
            __syncthreads();

            // ---- 2. stage gated inputs A[k][row] (h via sc1 reads) ----
            for (int e = tid; e < RPG * K; e += 512) {
                const int row = (e < K) ? 0 : 1;
                const int k   = e - row * K;
                const int r   = row0 + row;
                float v;
                if (k < 256) {
                    float b = (l == 0)
                        ? P.x[((size_t)r * Tt + t) * 256 + k]
                        : g_ldf(&P.out_h[((size_t)r * Tt + t) * 768 + (l - 1) * 256 + k]);
                    v = zbS[row] * b;
                } else if (k < 512) {
                    v = (t > 0)
                        ? g_ldf(&P.out_h[((size_t)r * Tt + (t - 1)) * 768 + l * 256 + (k - 256)])
                        : 0.f;
                } else {
                    float tp = (t > 0)
                        ? g_ldf(&P.out_h[((size_t)r * Tt + (t - 1)) * 768 + (l + 1) * 256 + (k - 512)])
                        : 0.f;
                    v = zoS[row] * tp;
                }
                A[k * RPG + row] = v;
            }
            __syncthreads();

            // ---- 3. GEMV: wave = k4-block chunk; lane = 2 cols x 2 rows ----
            {
                const int Kb  = K >> 5;              // k4-blocks per wave (24/16)
                const int kb0 = wave * Kb;
                const float4* __restrict__ W4ls =
                    (const float4*)P.w4s + ((size_t)shard * 3 + l) * 192 * 128;
                float acc0[RPG], acc1[RPG];
#pragma unroll
                for (int r = 0; r < RPG; ++r) { acc0[r] = 0.f; acc1[r] = 0.f; }
                for (int kb = kb0; kb < kb0 + Kb; ++kb) {
                    float4 w0 = W4ls[(size_t)kb * 128 + cl0];
                    float4 w1 = W4ls[(size_t)kb * 128 + cl1];
#pragma unroll
                    for (int q = 0; q < 4; ++q) {
                        float2 a = *(const float2*)&A[(kb * 4 + q) * RPG];
                        const float wq0 = (&w0.x)[q];
                        const float wq1 = (&w1.x)[q];
                        acc0[0] += wq0 * a.x; acc0[1] += wq0 * a.y;
                        acc1[0] += wq1 * a.x; acc1[1] += wq1 * a.y;
                    }
                }
#pragma unroll
                for (int r = 0; r < RPG; ++r) red[wave][cl0][r] = acc0[r];
#pragma unroll
                for (int r = 0; r < RPG; ++r) red[wave][cl1][r] = acc1[r];
            }

            // ---- 4. z column (shard 7): fp64, wave=row, lane=k strided ----
            if (shard == 7 && wave < RPG) {
                const float* __restrict__ wzl = P.wz + l * 768;
                double zp = 0.0;
                for (int k = lane; k < K; k += 64)
                    zp += (double)wzl[k] * (double)A[k * RPG + wave];
#pragma unroll
                for (int off = 32; off > 0; off >>= 1)
                    zp += __shfl_down(zp, off);
                if (lane == 0) {
                    double s = (double)bias[1024] + zp;
                    // round(clip((s+1)/2,0,1)) round-half-even == (s > 0)
                    float znew = (s > 0.0) ? 1.0f : 0.0f;
                    const int r = row0 + wave;
                    g_st(&P.zws[((size_t)r * 1539 + (t * 3 + l)) * 32], znew);
                    P.out_z[((size_t)r * Tt + t) * 3 + l] = znew;
                }
            }
            __syncthreads();

            // ---- 5. epilogue: threads 0..63 own (row, j) ----
            if (tid < RPG * 32) {
                const int row = tid >> 5;
                const int j   = tid & 31;
                const int r   = row0 + row;
                float s0 = bias[0 * Hh + shard * 32 + j];
                float s1 = bias[1 * Hh + shard * 32 + j];
                float s2 = bias[2 * Hh + shard * 32 + j];
                float s3 = bias[3 * Hh + shard * 32 + j];
#pragma unroll
                for (int w = 0; w < 8; ++w) {
                    s0 += red[w][0 * 32 + j][row];
                    s1 += red[w][1 * 32 + j][row];
                    s2 += red[w][2 * 32 + j][row];
                    s3 += red[w][3 * 32 + j][row];
                }
                float f = 1.0f / (1.0f + expf(-s0));
                float i = 1.0f / (1.0f + expf(-s1));
                float o = 1.0f / (1.0f + expf(-s2));
                float g = tanhf(s3);
                float zb_ = zbS[row];
                float zo_ = zoS[row];
                float c    = creg[l];
                float hold = hreg[l];
                float ig   = i * g;
                float cupd = f * c + ig;
                // z,zb in {0,1} exactly -> selects == reference arithmetic
                float cnew = (zo_ != 0.0f) ? ig : ((zb_ != 0.0f) ? cupd : c);
                float hnew = (zo_ == 0.0f && zb_ == 0.0f) ? hold : (o * tanhf(cnew));
                creg[l] = cnew;
                hreg[l] = hnew;
                g_st(&P.out_h[((size_t)r * Tt + t) * 768 + l * 256 + shard * 32 + j], hnew);
            }

            // ---- 6. 8-agent group barrier (r13..r20-proven RMW + poll) ----
            __syncthreads();   // drains vmcnt: h/z sc1 stores L3-visible
            if (tid == 0) {
                a_add(grpCnt, 1u);
                if (!broken) {
                    const unsigned int tgt = 8u * (stage + 1u);
                    unsigned int v = 0; int it = 0;
                    for (; it < WDOG; ++it) {
                        v = a_ld32(grpCnt);
                        if (v >= tgt) break;
                        __builtin_amdgcn_s_sleep(2);
                    }
                    broken = (v < tgt);
                }
            }
            __syncthreads();
            ++stage;
        }
    }
}

extern "C" void kernel_launch(void* const* d_in, const int* in_sizes, int n_in,
                              void* d_out, int out_size, void* d_ws, size_t ws_size,
                              hipStream_t stream) {
    (void)in_sizes; (void)n_in; (void)out_size;

    // dict order: x, Wb0,Wr0,Wt0,b0, Wb1,Wr1,Wt1,b1, Wb2,Wr2,Wt2,b2
    const float* x = (const float*)d_in[0];
    float* wsf = (float*)d_ws;

    // ws layout (floats)
    const size_t OFF_W4  = 0;                               // 8*3*192*128*4
    const size_t OFF_WZ  = OFF_W4 + (size_t)8 * 3 * 192 * 128 * 4;
    const size_t OFF_ZWS = OFF_WZ + 3 * 768 + 64;
    const size_t OFF_BAR = OFF_ZWS + (size_t)64 * 1539 * 32;
    const size_t OFF_ASN = OFF_BAR + 1024;
    const size_t OFF_END = OFF_ASN + 1024;

    float* w4s = wsf + OFF_W4;
    float* wz  = wsf + OFF_WZ;
    float* zws = wsf + OFF_ZWS;
    unsigned int* bar = (unsigned int*)(wsf + OFF_BAR);
    unsigned int* asn = (unsigned int*)(wsf + OFF_ASN);

    if (ws_size < OFF_END * sizeof(float)) return;     // ~22MB; ws proven >=110MB

    hipMemsetAsync(bar, 0, 2048 * sizeof(float), stream);   // bar + asn

    WSrc S;
    S.wb[0] = (const float*)d_in[1];  S.wr[0] = (const float*)d_in[2];  S.wt[0] = (const float*)d_in[3];
    S.wb[1] = (const float*)d_in[5];  S.wr[1] = (const float*)d_in[6];  S.wt[1] = (const float*)d_in[7];
    S.wb[2] = (const float*)d_in[9];  S.wr[2] = (const float*)d_in[10]; S.wt[2] = (const float*)d_in[11];
    build_w4s<<<2048, 256, 0, stream>>>(S, w4s, wz);

    PK pk;
    pk.x = x;
    pk.w4s = w4s;
    pk.wz = wz;
    pk.bias[0] = (const float*)d_in[4];
    pk.bias[1] = (const float*)d_in[8];
    pk.bias[2] = (const float*)d_in[12];
    pk.zws = zws;
    pk.bar = bar;
    pk.asn = asn;
    pk.out_h = (float*)d_out;
    pk.out_z = (float*)d_out + (size_t)Bb * Tt * 768;

    chain_kernel<<<256, 512, 0, stream>>>(pk);
}

// Round 22
// 8701.091 us; speedup vs baseline: 2.7629x; 1.2493x over previous
//
#include <hip/hip_runtime.h>
#include <cmath>

// HM-LSTM forward, MI355X. Round 22 = r21 (10.87ms, replay-proven) + STAGING
// PREFETCH. Of each stage's 1536 staged inputs only the bottom 512 (h(t,l-1))
// come from the immediately previous stage; recurrent h(t-1,l) and top
// zo*h(t-1,l+1) (zo=z(t-1,l), 3 stages old) are prefetchable during the
// PREVIOUS stage's GEMV into a ping-pong LDS buffer (for l=0 even the bottom:
// x, zb==1). Critical-path staging: 1536 -> 512 loads (l>=1) or 0 (l=0).
// Same gating arithmetic/order (absmax unchanged); all prefetch reads sc1 on
// >=1-stage-old unique slots (r21-proven replay-safe). Ballast resized to
// keep static LDS > 80KB (1 WG/CU). Everything else byte-identical to r21:
// per-shard dense pack, physical-XCD binding + fallback, 8-agent barrier,
// fp64 z (s>0), sc1 h-stores into d_out, sc1 consumer reads.

#define Hh    256
#define Bb    64
#define Tt    512
#define GC    1025
#define NGRP  32
#define RPG   2          // rows per group
#define WDOG  400000
#define WBOOT 2000000

__device__ __forceinline__ void g_st(float* p, float v) {
    __hip_atomic_store(p, v, __ATOMIC_RELAXED, __HIP_MEMORY_SCOPE_AGENT);
}
__device__ __forceinline__ float g_ldf(const float* p) {
    return __hip_atomic_load(p, __ATOMIC_RELAXED, __HIP_MEMORY_SCOPE_AGENT);
}
__device__ __forceinline__ unsigned int a_add(unsigned int* p, unsigned int v) {
    return __hip_atomic_fetch_add(p, v, __ATOMIC_RELAXED, __HIP_MEMORY_SCOPE_AGENT);
}
__device__ __forceinline__ unsigned int a_ld32(const unsigned int* p) {
    return __hip_atomic_load(p, __ATOMIC_RELAXED, __HIP_MEMORY_SCOPE_AGENT);
}
__device__ __forceinline__ unsigned int xcc_id() {
    unsigned int x;
    asm("s_getreg_b32 %0, hwreg(HW_REG_XCC_ID)" : "=s"(x));
    return x & 7u;
}

// ---------------------------------------------------------------------------
// Prep: per-shard dense pack:
//   w4s[(((s*3 + l)*192 + k/4)*128 + cl)*4 + k%4],  cl = gate*32 + jl,
//   source col = gate*256 + s*32 + jl.  z column -> wz[l*768+k].
// ---------------------------------------------------------------------------
struct WSrc { const float* wb[3]; const float* wr[3]; const float* wt[3]; };

__global__ __launch_bounds__(256) void build_w4s(WSrc S, float* __restrict__ w4s,
                                                 float* __restrict__ wz) {
    const int gk = blockIdx.x;           // 0..2047 = (l,k)
    int l, k;
    if (gk < 768)       { l = 0; k = gk; }
    else if (gk < 1536) { l = 1; k = gk - 768; }
    else                { l = 2; k = gk - 1536; }   // 512 rows
    const float* src;
    if (k < 256)      src = S.wb[l] + (size_t)k * GC;
    else if (k < 512) src = S.wr[l] + (size_t)(k - 256) * GC;
    else              src = S.wt[l] + (size_t)(k - 512) * GC;
#pragma unroll
    for (int it = 0; it < 4; ++it) {
        const int idx = it * 256 + threadIdx.x;     // 0..1023 = (s, cl)
        const int s  = idx >> 7;
        const int cl = idx & 127;
        const int scol = (cl >> 5) * 256 + s * 32 + (cl & 31);
        w4s[((((size_t)s * 3 + l) * 192 + (k >> 2)) * 128 + cl) * 4 + (k & 3)] = src[scol];
    }
    if (threadIdx.x == 0) wz[l * 768 + k] = src[1024];
}

// ---------------------------------------------------------------------------
// Main chain kernel. Grid 256 x 512, static LDS > 80KB (1 WG/CU verified).
// ---------------------------------------------------------------------------
struct PK {
    const float* x;         // (64,512,256)
    const float* w4s;       // per-shard dense packed weights
    const float* wz;        // [3][768] z columns
    const float* bias[3];   // (1025,)
    float* zws;             // z state: ((row*1539)+(t*3+l))*32
    unsigned int* bar;      // [g*32] group lines (32 groups)
    unsigned int* asn;      // [x*32] per-XCD cnt; [512] boot cnt
    float* out_h;           // (64,512,768) — doubles as h state
    float* out_z;           // (64,512,3)
};

__global__ __launch_bounds__(512, 1) void chain_kernel(PK P) {
    __shared__ float A0[768 * RPG];          // ping-pong staged inputs, 6KB
    __shared__ float A1[768 * RPG];          // 6KB
    __shared__ float red[8][128][3];         // 12KB
    __shared__ float zbS[RPG], zoS[RPG], zoN[RPG];
    __shared__ unsigned int sRole;
    __shared__ float ballast[14848];         // 58KB ballast -> total ~82KB

    const int tid   = threadIdx.x;
    const int lane  = tid & 63;
    const int wave  = tid >> 6;              // 0..7

    // Unprovable fake use so the static ballast is never elided.
    if (P.out_h == nullptr) {
        ballast[tid] = (float)tid;
        g_st(&P.out_z[tid], ballast[tid ^ 1]);
    }

    // ---- prologue: physical-XCD role assignment (one-time) ----
    if (tid == 0) {
        const unsigned int x = xcc_id();
        const unsigned int idx = a_add(&P.asn[x * 32], 1u);
        a_add(&P.asn[512], 1u);
        int it = 0;
        while (a_ld32(&P.asn[512]) < 256u && it < WBOOT) { __builtin_amdgcn_s_sleep(8); ++it; }
        bool bal = (it < WBOOT) && (idx < 32u);
        if (bal) {
#pragma unroll
            for (int q = 0; q < 8; ++q)
                if (a_ld32(&P.asn[q * 32]) != 32u) bal = false;
        }
        sRole = bal ? (idx * 8u + x)
                    : ((unsigned)(blockIdx.x >> 3) * 8u + (blockIdx.x & 7));
    }
    __syncthreads();
    const int group = sRole >> 3;
    const int shard = sRole & 7;
    const int row0  = group * RPG;

    unsigned int* grpCnt = P.bar + group * 32;
    unsigned int stage = 0;
    bool broken = false;

    float creg[3] = {0.f, 0.f, 0.f};
    float hreg[3] = {0.f, 0.f, 0.f};

    const int gi0 = lane >> 5;               // 0 or 1
    const int jl  = lane & 31;
    const int cl0 = gi0 * 32 + jl;
    const int cl1 = (gi0 + 2) * 32 + jl;

    float* Acur = A0;
    float* Anxt = A1;

    // ---- boot: fill A0 for stage (0,0): bottom=x (zb==1), rec=top=0 ----
    {
        const int row = tid >> 8;            // 0..1 (512 threads = RPG*256)
        const int kq  = tid & 255;
        const int r   = row0 + row;
        A0[kq * RPG + row]         = P.x[((size_t)r * Tt + 0) * 256 + kq];
        A0[(256 + kq) * RPG + row] = 0.f;
        A0[(512 + kq) * RPG + row] = 0.f;
    }

    for (int t = 0; t < Tt; ++t) {
#pragma unroll
        for (int l = 0; l < 3; ++l) {
            const int K = (l < 2) ? 768 : 512;
            const float* __restrict__ bias = P.bias[l];
            const bool hasNext = !(t == Tt - 1 && l == 2);
            const int tn = (l < 2) ? t : t + 1;
            const int ln = (l < 2) ? l + 1 : 0;

            // ---- 1. gate scalars for THIS stage + zo for NEXT stage ----
            if (tid < RPG) {
                const int r = row0 + tid;
                float zo = (t > 0) ? g_ldf(&P.zws[((size_t)r * 1539 + ((t - 1) * 3 + l)) * 32]) : 0.f;
                float zb = (l == 0) ? 1.f
                         : g_ldf(&P.zws[((size_t)r * 1539 + (t * 3 + l - 1)) * 32]);
                zoS[tid] = zo; zbS[tid] = zb;
            } else if (tid < 2 * RPG) {
                const int row = tid - RPG;
                const int r = row0 + row;
                zoN[row] = (hasNext && tn > 0)
                    ? g_ldf(&P.zws[((size_t)r * 1539 + ((tn - 1) * 3 + ln)) * 32]) : 0.f;
            }
            __syncthreads();

            // ---- 2. fixup: fresh bottom h * zb (l>=1 only; l==0 prefetched) ----
            if (l > 0) {
                const int row = tid >> 8;
                const int kq  = tid & 255;
                const int r   = row0 + row;
                float b = g_ldf(&P.out_h[((size_t)r * Tt + t) * 768 + (l - 1) * 256 + kq]);
                Acur[kq * RPG + row] = zbS[row] * b;
            }
            __syncthreads();

            // ---- 3. prefetch NEXT stage's rec/top (+x bottom if ln==0) ----
            if (hasNext) {
                const int row = tid >> 8;
                const int kq  = tid & 255;
                const int r   = row0 + row;
                float vr = (tn > 0)
                    ? g_ldf(&P.out_h[((size_t)r * Tt + (tn - 1)) * 768 + ln * 256 + kq]) : 0.f;
                Anxt[(256 + kq) * RPG + row] = vr;
                if (ln < 2) {
                    float vt = (tn > 0)
                        ? zoN[row] * g_ldf(&P.out_h[((size_t)r * Tt + (tn - 1)) * 768 + (ln + 1) * 256 + kq])
                        : 0.f;
                    Anxt[(512 + kq) * RPG + row] = vt;
                }
                if (ln == 0)
                    Anxt[kq * RPG + row] = P.x[((size_t)r * Tt + tn) * 256 + kq];
            }

            // ---- 4. GEMV from Acur ----
            {
                const int Kb  = K >> 5;
                const int kb0 = wave * Kb;
                const float4* __restrict__ W4ls =
                    (const float4*)P.w4s + ((size_t)shard * 3 + l) * 192 * 128;
                float acc0[RPG], acc1[RPG];
#pragma unroll
                for (int r = 0; r < RPG; ++r) { acc0[r] = 0.f; acc1[r] = 0.f; }
                for (int kb = kb0; kb < kb0 + Kb; ++kb) {
                    float4 w0 = W4ls[(size_t)kb * 128 + cl0];
                    float4 w1 = W4ls[(size_t)kb * 128 + cl1];
#pragma unroll
                    for (int q = 0; q < 4; ++q) {
                        float2 a = *(const float2*)&Acur[(kb * 4 + q) * RPG];
                        const float wq0 = (&w0.x)[q];
                        const float wq1 = (&w1.x)[q];
                        acc0[0] += wq0 * a.x; acc0[1] += wq0 * a.y;
                        acc1[0] += wq1 * a.x; acc1[1] += wq1 * a.y;
                    }
                }
#pragma unroll
                for (int r = 0; r < RPG; ++r) red[wave][cl0][r] = acc0[r];
#pragma unroll
                for (int r = 0; r < RPG; ++r) red[wave][cl1][r] = acc1[r];
            }

            // ---- 5. z column (shard 7): fp64, wave=row, lane=k strided ----
            if (shard == 7 && wave < RPG) {
                const float* __restrict__ wzl = P.wz + l * 768;
                double zp = 0.0;
                for (int k = lane; k < K; k += 64)
                    zp += (double)wzl[k] * (double)Acur[k * RPG + wave];
#pragma unroll
                for (int off = 32; off > 0; off >>= 1)
                    zp += __shfl_down(zp, off);
                if (lane == 0) {
                    double s = (double)bias[1024] + zp;
                    // round(clip((s+1)/2,0,1)) round-half-even == (s > 0)
                    float znew = (s > 0.0) ? 1.0f : 0.0f;
                    const int r = row0 + wave;
                    g_st(&P.zws[((size_t)r * 1539 + (t * 3 + l)) * 32], znew);
                    P.out_z[((size_t)r * Tt + t) * 3 + l] = znew;
                }
            }
            __syncthreads();

            // ---- 6. epilogue: threads 0..63 own (row, j) ----
            if (tid < RPG * 32) {
                const int row = tid >> 5;
                const int j   = tid & 31;
                const int r   = row0 + row;
                float s0 = bias[0 * Hh + shard * 32 + j];
                float s1 = bias[1 * Hh + shard * 32 + j];
                float s2 = bias[2 * Hh + shard * 32 + j];
                float s3 = bias[3 * Hh + shard * 32 + j];
#pragma unroll
                for (int w = 0; w < 8; ++w) {
                    s0 += red[w][0 * 32 + j][row];
                    s1 += red[w][1 * 32 + j][row];
                    s2 += red[w][2 * 32 + j][row];
                    s3 += red[w][3 * 32 + j][row];
                }
                float f = 1.0f / (1.0f + expf(-s0));
                float i = 1.0f / (1.0f + expf(-s1));
                float o = 1.0f / (1.0f + expf(-s2));
                float g = tanhf(s3);
                float zb_ = zbS[row];
                float zo_ = zoS[row];
                float c    = creg[l];
                float hold = hreg[l];
                float ig   = i * g;
                float cupd = f * c + ig;
                // z,zb in {0,1} exactly -> selects == reference arithmetic
                float cnew = (zo_ != 0.0f) ? ig : ((zb_ != 0.0f) ? cupd : c);
                float hnew = (zo_ == 0.0f && zb_ == 0.0f) ? hold : (o * tanhf(cnew));
                creg[l] = cnew;
                hreg[l] = hnew;
                g_st(&P.out_h[((size_t)r * Tt + t) * 768 + l * 256 + shard * 32 + j], hnew);
            }

            // ---- 7. 8-agent group barrier (r13..r21-proven RMW + poll) ----
            __syncthreads();   // drains vmcnt: h/z sc1 stores L3-visible
            if (tid == 0) {
                a_add(grpCnt, 1u);
                if (!broken) {
                    const unsigned int tgt = 8u * (stage + 1u);
                    unsigned int v = 0; int it = 0;
                    for (; it < WDOG; ++it) {
                        v = a_ld32(grpCnt);
                        if (v >= tgt) break;
                        __builtin_amdgcn_s_sleep(2);
                    }
                    broken = (v < tgt);
                }
            }
            __syncthreads();
            ++stage;

            // swap ping-pong buffers
            float* tmp = Acur; Acur = Anxt; Anxt = tmp;
        }
    }
}

extern "C" void kernel_launch(void* const* d_in, const int* in_sizes, int n_in,
                              void* d_out, int out_size, void* d_ws, size_t ws_size,
                              hipStream_t stream) {
    (void)in_sizes; (void)n_in; (void)out_size;

    // dict order: x, Wb0,Wr0,Wt0,b0, Wb1,Wr1,Wt1,b1, Wb2,Wr2,Wt2,b2
    const float* x = (const float*)d_in[0];
    float* wsf = (float*)d_ws;

    // ws layout (floats)
    const size_t OFF_W4  = 0;                               // 8*3*192*128*4
    const size_t OFF_WZ  = OFF_W4 + (size_t)8 * 3 * 192 * 128 * 4;
    const size_t OFF_ZWS = OFF_WZ + 3 * 768 + 64;
    const size_t OFF_BAR = OFF_ZWS + (size_t)64 * 1539 * 32;
    const size_t OFF_ASN = OFF_BAR + 1024;
    const size_t OFF_END = OFF_ASN + 1024;

    float* w4s = wsf + OFF_W4;
    float* wz  = wsf + OFF_WZ;
    float* zws = wsf + OFF_ZWS;
    unsigned int* bar = (unsigned int*)(wsf + OFF_BAR);
    unsigned int* asn = (unsigned int*)(wsf + OFF_ASN);

    if (ws_size < OFF_END * sizeof(float)) return;     // ~22MB; ws proven >=110MB

    hipMemsetAsync(bar, 0, 2048 * sizeof(float), stream);   // bar + asn

    WSrc S;
    S.wb[0] = (const float*)d_in[1];  S.wr[0] = (const float*)d_in[2];  S.wt[0] = (const float*)d_in[3];
    S.wb[1] = (const float*)d_in[5];  S.wr[1] = (const float*)d_in[6];  S.wt[1] = (const float*)d_in[7];
    S.wb[2] = (const float*)d_in[9];  S.wr[2] = (const float*)d_in[10]; S.wt[2] = (const float*)d_in[11];
    build_w4s<<<2048, 256, 0, stream>>>(S, w4s, wz);

    PK pk;
    pk.x = x;
    pk.w4s = w4s;
    pk.wz = wz;
    pk.bias[0] = (const float*)d_in[4];
    pk.bias[1] = (const float*)d_in[8];
    pk.bias[2] = (const float*)d_in[12];
    pk.zws = zws;
    pk.bar = bar;
    pk.asn = asn;
    pk.out_h = (float*)d_out;
    pk.out_z = (float*)d_out + (size_t)Bb * Tt * 768;

    chain_kernel<<<256, 512, 0, stream>>>(pk);
}